// Round 1
// baseline (828.601 us; speedup 1.0000x reference)
//
#include <hip/hip_runtime.h>
#include <hip/hip_bf16.h>

// GCN forward: 2-layer GCNConv + log_softmax.
// N=100000, E=3200000, F_IN=2000, H=16, C=3.
//
// Pipeline:
//  K0  memset cnt+cursor = 0
//  K1  count_k   : cnt[dst]++ over edges (int atomics)
//  K2  dinv_k    : dinv[i] = 1/sqrt(cnt[i]+1)   (self-loop included)
//  K3  scan_k    : rowptr = exclusive_scan(cnt)  (single 1024-thread block)
//  K4  scatter_k : CSR col array (edge sources bucketed by dst)
//  K5  gemm1     : t1s[row] = (x[row] @ W1) * dinv[row]      <-- 800MB read, dominant
//  K6  agg1      : h = relu(dinv[i]*(t1s[i]+sum t1s[col]) + b1);
//                  t2s[i] = (h @ W2) * dinv[i]   (fused via 16-lane shfl reduce)
//  K7  agg2      : logits = dinv[i]*(t2s[i]+sum t2s[col]) + b2; out = log_softmax

#define FIN   2000
#define HDIM  16
#define KB    40          // K-chunk staged in LDS
#define NCHUNK (FIN / KB) // 50
#define KSTRIDE 65        // padded k-stride (words) of transposed x tile

__global__ void count_k(const int* __restrict__ dst, int* __restrict__ cnt, int e) {
    int i = blockIdx.x * 256 + threadIdx.x;
    if (i < e) atomicAdd(&cnt[dst[i]], 1);
}

__global__ void dinv_k(const int* __restrict__ cnt, float* __restrict__ dinv, int n) {
    int i = blockIdx.x * 256 + threadIdx.x;
    if (i < n) dinv[i] = 1.0f / sqrtf((float)(cnt[i] + 1));
}

__global__ __launch_bounds__(1024) void scan_k(const int* __restrict__ cnt,
                                               int* __restrict__ rowptr, int n) {
    __shared__ int sdata[1024];
    int tid = threadIdx.x;
    int chunk = (n + 1023) >> 10;
    int s0 = tid * chunk;
    int s1 = s0 + chunk; if (s1 > n) s1 = n;
    int sum = 0;
    for (int i = s0; i < s1; ++i) sum += cnt[i];
    sdata[tid] = sum;
    __syncthreads();
    for (int off = 1; off < 1024; off <<= 1) {
        int v = sdata[tid];
        int u = (tid >= off) ? sdata[tid - off] : 0;
        __syncthreads();
        sdata[tid] = v + u;
        __syncthreads();
    }
    int run = sdata[tid] - sum;   // exclusive prefix
    for (int i = s0; i < s1; ++i) { rowptr[i] = run; run += cnt[i]; }
    if (tid == 0) rowptr[n] = sdata[1023];
}

__global__ void scatter_k(const int* __restrict__ src, const int* __restrict__ dst,
                          const int* __restrict__ rowptr, int* __restrict__ cursor,
                          int* __restrict__ col, int e) {
    int i = blockIdx.x * 256 + threadIdx.x;
    if (i < e) {
        int d = dst[i];
        int pos = rowptr[d] + atomicAdd(&cursor[d], 1);
        col[pos] = src[i];
    }
}

// ---- big GEMM: t1s = (x @ W1) * dinv[row] -------------------------------
// 1 wave per block, 64 rows per block. x tile staged in LDS transposed
// [k][row] with k-stride 65 (conflict-free reads). Double-buffered register
// staging: loads for chunk c+1 in flight while computing chunk c.
__global__ __launch_bounds__(64) void gemm1(const float* __restrict__ x,
                                            const float* __restrict__ W1,
                                            const float* __restrict__ dinv,
                                            float* __restrict__ t1s, int n) {
    __shared__ float xT[2][KB * KSTRIDE];
    const int lane = threadIdx.x;
    const long base = (long)blockIdx.x * 64;

    float4 st[10];

    // stage_load(c): 640 float4 jobs; job j -> row j/10, k4 j%10 (coalesced per row)
#define STAGE_LOAD(c)                                                       \
    {                                                                       \
        _Pragma("unroll")                                                   \
        for (int i = 0; i < 10; ++i) {                                      \
            int job = i * 64 + lane;                                        \
            int jr = job / 10, jk = job - jr * 10;                          \
            long gr = base + jr; if (gr >= n) gr = n - 1;                   \
            st[i] = *(const float4*)(x + gr * FIN + (c) * KB + jk * 4);     \
        }                                                                   \
    }
#define STAGE_WRITE(bsel)                                                   \
    {                                                                       \
        float* p = &xT[(bsel)][0];                                          \
        _Pragma("unroll")                                                   \
        for (int i = 0; i < 10; ++i) {                                      \
            int job = i * 64 + lane;                                        \
            int jr = job / 10, jk = job - jr * 10;                          \
            p[(jk * 4 + 0) * KSTRIDE + jr] = st[i].x;                       \
            p[(jk * 4 + 1) * KSTRIDE + jr] = st[i].y;                       \
            p[(jk * 4 + 2) * KSTRIDE + jr] = st[i].z;                       \
            p[(jk * 4 + 3) * KSTRIDE + jr] = st[i].w;                       \
        }                                                                   \
    }

    float acc[HDIM];
#pragma unroll
    for (int j = 0; j < HDIM; ++j) acc[j] = 0.0f;

    STAGE_LOAD(0);
    STAGE_WRITE(0);

    for (int c = 0; c < NCHUNK; ++c) {
        int b = c & 1;
        if (c + 1 < NCHUNK) STAGE_LOAD(c + 1);
        const float* w0 = W1 + c * KB * HDIM;
#pragma unroll 4
        for (int k = 0; k < KB; ++k) {
            float xv = xT[b][k * KSTRIDE + lane];
            const float* w = w0 + k * HDIM;
#pragma unroll
            for (int j = 0; j < HDIM; ++j) acc[j] = fmaf(xv, w[j], acc[j]);
        }
        if (c + 1 < NCHUNK) STAGE_WRITE((c + 1) & 1);
    }

    long row = base + lane;
    long rc = row < n ? row : n - 1;
    float s = dinv[rc];
    if (row < n) {
        float4* o = (float4*)(t1s + row * HDIM);
        o[0] = make_float4(acc[0] * s, acc[1] * s, acc[2] * s, acc[3] * s);
        o[1] = make_float4(acc[4] * s, acc[5] * s, acc[6] * s, acc[7] * s);
        o[2] = make_float4(acc[8] * s, acc[9] * s, acc[10] * s, acc[11] * s);
        o[3] = make_float4(acc[12] * s, acc[13] * s, acc[14] * s, acc[15] * s);
    }
#undef STAGE_LOAD
#undef STAGE_WRITE
}

// ---- aggregation 1 + relu + (h @ W2) fused ------------------------------
// 16 lanes per node (one per hidden dim).
__global__ __launch_bounds__(256) void agg1(const float* __restrict__ t1s,
                                            const int* __restrict__ rowptr,
                                            const int* __restrict__ col,
                                            const float* __restrict__ dinv,
                                            const float* __restrict__ b1,
                                            const float* __restrict__ W2,
                                            float* __restrict__ t2s, int n) {
    int tid = blockIdx.x * 256 + threadIdx.x;
    int node = tid >> 4;
    int j = tid & 15;
    if (node >= n) return;
    float acc = t1s[node * HDIM + j];             // self-loop (dinv[src] pre-folded)
    int e0 = rowptr[node], e1 = rowptr[node + 1];
    for (int e = e0; e < e1; ++e) {
        int s = col[e];
        acc += t1s[s * HDIM + j];
    }
    float dn = dinv[node];
    float h = acc * dn + b1[j];
    h = h > 0.0f ? h : 0.0f;
    // t2[c] = sum_j h_j * W2[j][c], 16-lane butterfly reduce
    float p0 = h * W2[j * 3 + 0];
    float p1 = h * W2[j * 3 + 1];
    float p2 = h * W2[j * 3 + 2];
#pragma unroll
    for (int off = 8; off > 0; off >>= 1) {
        p0 += __shfl_xor(p0, off, 16);
        p1 += __shfl_xor(p1, off, 16);
        p2 += __shfl_xor(p2, off, 16);
    }
    if (j == 0) {
        *(float4*)(t2s + node * 4) = make_float4(p0 * dn, p1 * dn, p2 * dn, 0.0f);
    }
}

// ---- aggregation 2 + bias + log_softmax ---------------------------------
__global__ __launch_bounds__(256) void agg2(const float* __restrict__ t2s,
                                            const int* __restrict__ rowptr,
                                            const int* __restrict__ col,
                                            const float* __restrict__ dinv,
                                            const float* __restrict__ b2,
                                            float* __restrict__ out, int n) {
    int node = blockIdx.x * 256 + threadIdx.x;
    if (node >= n) return;
    float4 a = *(const float4*)(t2s + node * 4);
    float a0 = a.x, a1 = a.y, a2 = a.z;
    int e0 = rowptr[node], e1 = rowptr[node + 1];
    for (int e = e0; e < e1; ++e) {
        int s = col[e];
        float4 v = *(const float4*)(t2s + s * 4);
        a0 += v.x; a1 += v.y; a2 += v.z;
    }
    float dn = dinv[node];
    float l0 = a0 * dn + b2[0];
    float l1 = a1 * dn + b2[1];
    float l2 = a2 * dn + b2[2];
    float m = fmaxf(l0, fmaxf(l1, l2));
    float lse = logf(expf(l0 - m) + expf(l1 - m) + expf(l2 - m)) + m;
    out[node * 3 + 0] = l0 - lse;
    out[node * 3 + 1] = l1 - lse;
    out[node * 3 + 2] = l2 - lse;
}

extern "C" void kernel_launch(void* const* d_in, const int* in_sizes, int n_in,
                              void* d_out, int out_size, void* d_ws, size_t ws_size,
                              hipStream_t stream) {
    const float* x  = (const float*)d_in[0];
    const int*   ei = (const int*)d_in[1];
    const float* W1 = (const float*)d_in[2];
    const float* b1 = (const float*)d_in[3];
    const float* W2 = (const float*)d_in[4];
    const float* b2 = (const float*)d_in[5];
    const int N = in_sizes[0] / FIN;
    const int E = in_sizes[1] / 2;
    const int* src = ei;
    const int* dst = ei + E;

    char* ws = (char*)d_ws;
    auto alloc = [&](size_t bytes) {
        char* p = ws;
        ws += (bytes + 255) & ~(size_t)255;
        return p;
    };
    size_t npad = ((size_t)N * 4 + 255) & ~(size_t)255;
    int*   cnt    = (int*)alloc(N * 4);
    int*   cursor = (int*)alloc(N * 4);     // adjacent to cnt: one memset covers both
    int*   rowptr = (int*)alloc((size_t)(N + 1) * 4);
    float* dinv   = (float*)alloc(N * 4);
    int*   col    = (int*)alloc((size_t)E * 4);
    float* t1s    = (float*)alloc((size_t)N * HDIM * 4);
    float* t2s    = (float*)alloc((size_t)N * 4 * 4);

    hipMemsetAsync(cnt, 0, npad * 2, stream);
    count_k<<<(E + 255) / 256, 256, 0, stream>>>(dst, cnt, E);
    dinv_k<<<(N + 255) / 256, 256, 0, stream>>>(cnt, dinv, N);
    scan_k<<<1, 1024, 0, stream>>>(cnt, rowptr, N);
    scatter_k<<<(E + 255) / 256, 256, 0, stream>>>(src, dst, rowptr, cursor, col, E);
    gemm1<<<(N + 63) / 64, 64, 0, stream>>>(x, W1, dinv, t1s, N);
    agg1<<<(N * 16 + 255) / 256, 256, 0, stream>>>(t1s, rowptr, col, dinv, b1, W2, t2s, N);
    agg2<<<(N + 255) / 256, 256, 0, stream>>>(t2s, rowptr, col, dinv, b2, (float*)d_out, N);
}

// Round 2
// 827.399 us; speedup vs baseline: 1.0015x; 1.0015x over previous
//
#include <hip/hip_runtime.h>
#include <hip/hip_bf16.h>

// GCN forward: 2-layer GCNConv + log_softmax.
// N=100000, E=3200000, F_IN=2000, H=16, C=3.
//
// Pipeline:
//  K0  zero_k    : cnt+cursor = 0 (custom kernel; hipMemsetAsync's
//                  fillBufferAligned took ~510us for 800KB in-graph — R1 fix)
//  K1  count_k   : cnt[dst]++ over edges (int atomics)
//  K2  dinv_k    : dinv[i] = 1/sqrt(cnt[i]+1)   (self-loop included)
//  K3  scan_k    : rowptr = exclusive_scan(cnt)  (single 1024-thread block)
//  K4  scatter_k : CSR col array (edge sources bucketed by dst)
//  K5  gemm1     : t1s[row] = (x[row] @ W1) * dinv[row]      <-- 800MB read, dominant
//  K6  agg1      : h = relu(dinv[i]*(t1s[i]+sum t1s[col]) + b1);
//                  t2s[i] = (h @ W2) * dinv[i]   (fused via 16-lane shfl reduce)
//  K7  agg2      : logits = dinv[i]*(t2s[i]+sum t2s[col]) + b2; out = log_softmax

#define FIN   2000
#define HDIM  16
#define KB    40          // K-chunk staged in LDS
#define NCHUNK (FIN / KB) // 50
#define KSTRIDE 65        // padded k-stride (words) of transposed x tile

__global__ void zero_k(int4* __restrict__ p, int n4) {
    int i = blockIdx.x * 256 + threadIdx.x;
    if (i < n4) p[i] = make_int4(0, 0, 0, 0);
}

__global__ void count_k(const int* __restrict__ dst, int* __restrict__ cnt, int e) {
    int i = blockIdx.x * 256 + threadIdx.x;
    if (i < e) atomicAdd(&cnt[dst[i]], 1);
}

__global__ void dinv_k(const int* __restrict__ cnt, float* __restrict__ dinv, int n) {
    int i = blockIdx.x * 256 + threadIdx.x;
    if (i < n) dinv[i] = 1.0f / sqrtf((float)(cnt[i] + 1));
}

__global__ __launch_bounds__(1024) void scan_k(const int* __restrict__ cnt,
                                               int* __restrict__ rowptr, int n) {
    __shared__ int sdata[1024];
    int tid = threadIdx.x;
    int chunk = (n + 1023) >> 10;
    int s0 = tid * chunk;
    int s1 = s0 + chunk; if (s1 > n) s1 = n;
    int sum = 0;
    for (int i = s0; i < s1; ++i) sum += cnt[i];
    sdata[tid] = sum;
    __syncthreads();
    for (int off = 1; off < 1024; off <<= 1) {
        int v = sdata[tid];
        int u = (tid >= off) ? sdata[tid - off] : 0;
        __syncthreads();
        sdata[tid] = v + u;
        __syncthreads();
    }
    int run = sdata[tid] - sum;   // exclusive prefix
    for (int i = s0; i < s1; ++i) { rowptr[i] = run; run += cnt[i]; }
    if (tid == 0) rowptr[n] = sdata[1023];
}

__global__ void scatter_k(const int* __restrict__ src, const int* __restrict__ dst,
                          const int* __restrict__ rowptr, int* __restrict__ cursor,
                          int* __restrict__ col, int e) {
    int i = blockIdx.x * 256 + threadIdx.x;
    if (i < e) {
        int d = dst[i];
        int pos = rowptr[d] + atomicAdd(&cursor[d], 1);
        col[pos] = src[i];
    }
}

// ---- big GEMM: t1s = (x @ W1) * dinv[row] -------------------------------
// 1 wave per block, 64 rows per block. x tile staged in LDS transposed
// [k][row] with k-stride 65 (conflict-free reads). Double-buffered register
// staging: loads for chunk c+1 in flight while computing chunk c.
__global__ __launch_bounds__(64) void gemm1(const float* __restrict__ x,
                                            const float* __restrict__ W1,
                                            const float* __restrict__ dinv,
                                            float* __restrict__ t1s, int n) {
    __shared__ float xT[2][KB * KSTRIDE];
    const int lane = threadIdx.x;
    const long base = (long)blockIdx.x * 64;

    float4 st[10];

    // stage_load(c): 640 float4 jobs; job j -> row j/10, k4 j%10 (coalesced per row)
#define STAGE_LOAD(c)                                                       \
    {                                                                       \
        _Pragma("unroll")                                                   \
        for (int i = 0; i < 10; ++i) {                                      \
            int job = i * 64 + lane;                                        \
            int jr = job / 10, jk = job - jr * 10;                          \
            long gr = base + jr; if (gr >= n) gr = n - 1;                   \
            st[i] = *(const float4*)(x + gr * FIN + (c) * KB + jk * 4);     \
        }                                                                   \
    }
#define STAGE_WRITE(bsel)                                                   \
    {                                                                       \
        float* p = &xT[(bsel)][0];                                          \
        _Pragma("unroll")                                                   \
        for (int i = 0; i < 10; ++i) {                                      \
            int job = i * 64 + lane;                                        \
            int jr = job / 10, jk = job - jr * 10;                          \
            p[(jk * 4 + 0) * KSTRIDE + jr] = st[i].x;                       \
            p[(jk * 4 + 1) * KSTRIDE + jr] = st[i].y;                       \
            p[(jk * 4 + 2) * KSTRIDE + jr] = st[i].z;                       \
            p[(jk * 4 + 3) * KSTRIDE + jr] = st[i].w;                       \
        }                                                                   \
    }

    float acc[HDIM];
#pragma unroll
    for (int j = 0; j < HDIM; ++j) acc[j] = 0.0f;

    STAGE_LOAD(0);
    STAGE_WRITE(0);

    for (int c = 0; c < NCHUNK; ++c) {
        int b = c & 1;
        if (c + 1 < NCHUNK) STAGE_LOAD(c + 1);
        const float* w0 = W1 + c * KB * HDIM;
#pragma unroll 4
        for (int k = 0; k < KB; ++k) {
            float xv = xT[b][k * KSTRIDE + lane];
            const float* w = w0 + k * HDIM;
#pragma unroll
            for (int j = 0; j < HDIM; ++j) acc[j] = fmaf(xv, w[j], acc[j]);
        }
        if (c + 1 < NCHUNK) STAGE_WRITE((c + 1) & 1);
    }

    long row = base + lane;
    long rc = row < n ? row : n - 1;
    float s = dinv[rc];
    if (row < n) {
        float4* o = (float4*)(t1s + row * HDIM);
        o[0] = make_float4(acc[0] * s, acc[1] * s, acc[2] * s, acc[3] * s);
        o[1] = make_float4(acc[4] * s, acc[5] * s, acc[6] * s, acc[7] * s);
        o[2] = make_float4(acc[8] * s, acc[9] * s, acc[10] * s, acc[11] * s);
        o[3] = make_float4(acc[12] * s, acc[13] * s, acc[14] * s, acc[15] * s);
    }
#undef STAGE_LOAD
#undef STAGE_WRITE
}

// ---- aggregation 1 + relu + (h @ W2) fused ------------------------------
// 16 lanes per node (one per hidden dim).
__global__ __launch_bounds__(256) void agg1(const float* __restrict__ t1s,
                                            const int* __restrict__ rowptr,
                                            const int* __restrict__ col,
                                            const float* __restrict__ dinv,
                                            const float* __restrict__ b1,
                                            const float* __restrict__ W2,
                                            float* __restrict__ t2s, int n) {
    int tid = blockIdx.x * 256 + threadIdx.x;
    int node = tid >> 4;
    int j = tid & 15;
    if (node >= n) return;
    float acc = t1s[node * HDIM + j];             // self-loop (dinv[src] pre-folded)
    int e0 = rowptr[node], e1 = rowptr[node + 1];
    for (int e = e0; e < e1; ++e) {
        int s = col[e];
        acc += t1s[s * HDIM + j];
    }
    float dn = dinv[node];
    float h = acc * dn + b1[j];
    h = h > 0.0f ? h : 0.0f;
    // t2[c] = sum_j h_j * W2[j][c], 16-lane butterfly reduce
    float p0 = h * W2[j * 3 + 0];
    float p1 = h * W2[j * 3 + 1];
    float p2 = h * W2[j * 3 + 2];
#pragma unroll
    for (int off = 8; off > 0; off >>= 1) {
        p0 += __shfl_xor(p0, off, 16);
        p1 += __shfl_xor(p1, off, 16);
        p2 += __shfl_xor(p2, off, 16);
    }
    if (j == 0) {
        *(float4*)(t2s + node * 4) = make_float4(p0 * dn, p1 * dn, p2 * dn, 0.0f);
    }
}

// ---- aggregation 2 + bias + log_softmax ---------------------------------
__global__ __launch_bounds__(256) void agg2(const float* __restrict__ t2s,
                                            const int* __restrict__ rowptr,
                                            const int* __restrict__ col,
                                            const float* __restrict__ dinv,
                                            const float* __restrict__ b2,
                                            float* __restrict__ out, int n) {
    int node = blockIdx.x * 256 + threadIdx.x;
    if (node >= n) return;
    float4 a = *(const float4*)(t2s + node * 4);
    float a0 = a.x, a1 = a.y, a2 = a.z;
    int e0 = rowptr[node], e1 = rowptr[node + 1];
    for (int e = e0; e < e1; ++e) {
        int s = col[e];
        float4 v = *(const float4*)(t2s + s * 4);
        a0 += v.x; a1 += v.y; a2 += v.z;
    }
    float dn = dinv[node];
    float l0 = a0 * dn + b2[0];
    float l1 = a1 * dn + b2[1];
    float l2 = a2 * dn + b2[2];
    float m = fmaxf(l0, fmaxf(l1, l2));
    float lse = logf(expf(l0 - m) + expf(l1 - m) + expf(l2 - m)) + m;
    out[node * 3 + 0] = l0 - lse;
    out[node * 3 + 1] = l1 - lse;
    out[node * 3 + 2] = l2 - lse;
}

extern "C" void kernel_launch(void* const* d_in, const int* in_sizes, int n_in,
                              void* d_out, int out_size, void* d_ws, size_t ws_size,
                              hipStream_t stream) {
    const float* x  = (const float*)d_in[0];
    const int*   ei = (const int*)d_in[1];
    const float* W1 = (const float*)d_in[2];
    const float* b1 = (const float*)d_in[3];
    const float* W2 = (const float*)d_in[4];
    const float* b2 = (const float*)d_in[5];
    const int N = in_sizes[0] / FIN;
    const int E = in_sizes[1] / 2;
    const int* src = ei;
    const int* dst = ei + E;

    char* ws = (char*)d_ws;
    auto alloc = [&](size_t bytes) {
        char* p = ws;
        ws += (bytes + 255) & ~(size_t)255;
        return p;
    };
    size_t npad = ((size_t)N * 4 + 255) & ~(size_t)255;
    int*   cnt    = (int*)alloc(N * 4);
    int*   cursor = (int*)alloc(N * 4);     // adjacent to cnt: one zero_k covers both
    int*   rowptr = (int*)alloc((size_t)(N + 1) * 4);
    float* dinv   = (float*)alloc(N * 4);
    int*   col    = (int*)alloc((size_t)E * 4);
    float* t1s    = (float*)alloc((size_t)N * HDIM * 4);
    float* t2s    = (float*)alloc((size_t)N * 4 * 4);

    int n4 = (int)(npad * 2 / 16);          // cnt+cursor region as int4s
    zero_k<<<(n4 + 255) / 256, 256, 0, stream>>>((int4*)cnt, n4);
    count_k<<<(E + 255) / 256, 256, 0, stream>>>(dst, cnt, E);
    dinv_k<<<(N + 255) / 256, 256, 0, stream>>>(cnt, dinv, N);
    scan_k<<<1, 1024, 0, stream>>>(cnt, rowptr, N);
    scatter_k<<<(E + 255) / 256, 256, 0, stream>>>(src, dst, rowptr, cursor, col, E);
    gemm1<<<(N + 63) / 64, 64, 0, stream>>>(x, W1, dinv, t1s, N);
    agg1<<<(N * 16 + 255) / 256, 256, 0, stream>>>(t1s, rowptr, col, dinv, b1, W2, t2s, N);
    agg2<<<(N + 255) / 256, 256, 0, stream>>>(t2s, rowptr, col, dinv, b2, (float*)d_out, N);
}